// Round 5
// baseline (1599.505 us; speedup 1.0000x reference)
//
#include <hip/hip_runtime.h>
#include <stdint.h>

typedef float f32x4 __attribute__((ext_vector_type(4)));
typedef short s16x8 __attribute__((ext_vector_type(8)));
typedef short s16x4 __attribute__((ext_vector_type(4)));
typedef uint32_t u32x4 __attribute__((ext_vector_type(4)));

#define HDIM 128
#define TLEN 512
#define BT 16

__device__ __forceinline__ unsigned short f2bf(float f) {
    union { float f; uint32_t u; } v; v.f = f;
    uint32_t r = v.u + 0x7FFFu + ((v.u >> 16) & 1u);
    return (unsigned short)(r >> 16);
}
__device__ __forceinline__ float bfhi(uint32_t u){ union{uint32_t u;float f;}v; v.u = u & 0xFFFF0000u; return v.f; }
__device__ __forceinline__ float bflo(uint32_t u){ union{uint32_t u;float f;}v; v.u = u << 16; return v.f; }

__device__ __forceinline__ float sigmoidf_(float x){
    float e = __expf(-x);
    return __builtin_amdgcn_rcpf(1.0f + e);
}
__device__ __forceinline__ float tanhf_(float x){
    float e = __expf(2.0f * x);
    return 1.0f - 2.0f * __builtin_amdgcn_rcpf(1.0f + e);
}

#define MFMA16(A, B, C) __builtin_amdgcn_mfma_f32_16x16x32_bf16((A), (B), (C), 0, 0, 0)

__global__ __launch_bounds__(256, 1) void lstm_fused_kernel(
    const float* __restrict__ x,      // (2048,512,1)
    const float* __restrict__ Wih0,   // (512,1)
    const float* __restrict__ Whh0,   // (512,128)
    const float* __restrict__ bih0,
    const float* __restrict__ bhh0,
    const float* __restrict__ Wih1,   // (512,128)
    const float* __restrict__ Whh1,   // (512,128)
    const float* __restrict__ bih1,
    const float* __restrict__ bhh1,
    const float* __restrict__ W1,     // (64,128)
    const float* __restrict__ b1,     // (64)
    const float* __restrict__ W2,     // (8,64)
    const float* __restrict__ b2,     // (8)
    float* __restrict__ out)          // (2048,8)
{
    // No weights in LDS — only h ping-pong, bias broadcast tables, head scratch.
    __shared__ __align__(16) short h0f0[2048], h0f1[2048];
    __shared__ __align__(16) short h1f0[2048], h1f1[2048];
    __shared__ __align__(16) float    b1lds[4][8][16];   // [w][t2][row16] f32 (C-init)
    __shared__ __align__(16) uint32_t b0wx[4][8][16];    // [w][t2][row16] packed (b0 lo, wx hi) bf16
    __shared__ __align__(16) float headH[16 * HDIM];
    __shared__ __align__(16) float headL[16 * 64];

    const int tid = threadIdx.x;
    const int w = tid >> 6;     // wave 0..3 ; owns units [32w, 32w+32)
    const int l = tid & 63;
    const int n = l & 15;       // batch col
    const int q = l >> 4;       // k-group / row-quad
    const int b0 = blockIdx.x * BT;
    const float* xrow = x + (size_t)(b0 + n) * TLEN;

    // ---- ALL recurrent weights into registers (bf16 fragments) ----
    // tile t2 = gate*2 + half; rows = (t2>>1)*128 + 32w + 16*(t2&1) + [0,16)
    s16x8 w0f[4][8], wi1f[4][8], wh1f[4][8];   // [k-chunk][tile]
    #pragma unroll
    for (int c = 0; c < 4; ++c) {
        #pragma unroll
        for (int t2 = 0; t2 < 8; ++t2) {
            const int row = (t2 >> 1) * 128 + 32 * w + 16 * (t2 & 1) + n;
            const int k0 = c * 32 + q * 8;
            const float* p0 = Whh0 + row * HDIM + k0;
            const float* p1 = Wih1 + row * HDIM + k0;
            const float* p2 = Whh1 + row * HDIM + k0;
            s16x8 a0, a1, a2;
            #pragma unroll
            for (int j = 0; j < 8; ++j) {
                a0[j] = (short)f2bf(p0[j]);
                a1[j] = (short)f2bf(p1[j]);
                a2[j] = (short)f2bf(p2[j]);
            }
            w0f[c][t2] = a0; wi1f[c][t2] = a1; wh1f[c][t2] = a2;
        }
    }

    // ---- bias broadcast tables ----
    for (int idx = tid; idx < 512; idx += 256) {
        const int ww = idx >> 7, t2 = (idx >> 4) & 7, j = idx & 15;
        const int row = (t2 >> 1) * 128 + 32 * ww + 16 * (t2 & 1) + j;
        b1lds[ww][t2][j] = bih1[row] + bhh1[row];
        b0wx[ww][t2][j] = ((uint32_t)f2bf(Wih0[row]) << 16) | f2bf(bih0[row] + bhh0[row]);
    }
    // zero h1[-1]
    for (int s2 = tid; s2 < 1024; s2 += 256) ((uint32_t*)h1f1)[s2] = 0u;

    // B-fragment write slots for this lane's unit quads (h=0 / h=1)
    const int ub0 = 32 * w + 4 * q;
    const int ub1 = ub0 + 16;
    const int fo0 = (((ub0 >> 5) * 64) + n + 16 * ((ub0 >> 3) & 3)) * 8 + (ub0 & 7);
    const int fo1 = (((ub1 >> 5) * 64) + n + 16 * ((ub1 >> 3) & 3)) * 8 + (ub1 & 7);

    float c0_[2][4] = {{0.f,0.f,0.f,0.f},{0.f,0.f,0.f,0.f}};
    float c1_[2][4] = {{0.f,0.f,0.f,0.f},{0.f,0.f,0.f,0.f}};

    __syncthreads();   // bias tables + h1f1 visible

    // ---- prologue: h0[0] = pointwise(b0 + wx*x[0]) ; h0[-1]=0 so no MFMA ----
    {
        const float x0 = xrow[0];
        #pragma unroll
        for (int h = 0; h < 2; ++h) {
            u32x4 bw[4];
            #pragma unroll
            for (int g = 0; g < 4; ++g) bw[g] = *(const u32x4*)&b0wx[w][g * 2 + h][q * 4];
            s16x4 hw;
            #pragma unroll
            for (int r = 0; r < 4; ++r) {
                const float pi = fmaf(bfhi(bw[0][r]), x0, bflo(bw[0][r]));
                const float pg = fmaf(bfhi(bw[2][r]), x0, bflo(bw[2][r]));
                const float po = fmaf(bfhi(bw[3][r]), x0, bflo(bw[3][r]));
                const float ig = sigmoidf_(pi);
                const float gg = tanhf_(pg);
                const float og = sigmoidf_(po);
                const float cc = ig * gg;          // f * c(-1) = 0
                c0_[h][r] = cc;
                hw[r] = (short)f2bf(og * tanhf_(cc));
            }
            *(s16x4*)&h0f0[h ? fo1 : fo0] = hw;
        }
    }
    __syncthreads();

// layer-1 pointwise for half H (consumes a1_ tiles {2g+H})
#define PH4(H, BUF, FO) {                                                     \
    s16x4 hw;                                                                 \
    _Pragma("unroll")                                                         \
    for (int r = 0; r < 4; ++r) {                                             \
        const float ig = sigmoidf_(a1_[0 + H][r]);                            \
        const float fg = sigmoidf_(a1_[2 + H][r]);                            \
        const float gg = tanhf_(a1_[4 + H][r]);                               \
        const float og = sigmoidf_(a1_[6 + H][r]);                            \
        const float cc = fmaf(fg, c1_[H][r], ig * gg);                        \
        c1_[H][r] = cc;                                                       \
        hw[r] = (short)f2bf(og * tanhf_(cc));                                 \
    }                                                                         \
    *(s16x4*)&(BUF)[FO] = hw; }

// layer-0 pointwise for half H (consumes a0_ tiles {2g+H}, bias+wx from LDS)
#define PH2(H, BUF, FO, XN) {                                                 \
    const u32x4 bw0 = *(const u32x4*)&b0wx[w][0 + H][q * 4];                  \
    const u32x4 bw1 = *(const u32x4*)&b0wx[w][2 + H][q * 4];                  \
    const u32x4 bw2 = *(const u32x4*)&b0wx[w][4 + H][q * 4];                  \
    const u32x4 bw3 = *(const u32x4*)&b0wx[w][6 + H][q * 4];                  \
    s16x4 hw;                                                                 \
    _Pragma("unroll")                                                         \
    for (int r = 0; r < 4; ++r) {                                             \
        const float pi = a0_[0 + H][r] + fmaf(bfhi(bw0[r]), (XN), bflo(bw0[r])); \
        const float pf = a0_[2 + H][r] + fmaf(bfhi(bw1[r]), (XN), bflo(bw1[r])); \
        const float pg = a0_[4 + H][r] + fmaf(bfhi(bw2[r]), (XN), bflo(bw2[r])); \
        const float po = a0_[6 + H][r] + fmaf(bfhi(bw3[r]), (XN), bflo(bw3[r])); \
        const float ig = sigmoidf_(pi);                                       \
        const float fg = sigmoidf_(pf);                                       \
        const float gg = tanhf_(pg);                                          \
        const float og = sigmoidf_(po);                                       \
        const float cc = fmaf(fg, c0_[H][r], ig * gg);                        \
        c0_[H][r] = cc;                                                       \
        hw[r] = (short)f2bf(og * tanhf_(cc));                                 \
    }                                                                         \
    *(s16x4*)&(BUF)[FO] = hw; }

// NOTE: tile t2 remapped for PH macros: a?_[idx] where idx = g*2+H; arrays are
// ordered [t2] with t2 = g*2+half, so a1_[2g+H] == tile (g, H). The macros
// above index a1_[0+H], a1_[2+H], a1_[4+H], a1_[6+H] == gates i,f,g,o. OK.

#define ITER(T, R0, R1, W0B, W1B) do {                                        \
    const float xn_ = xrow[(T) + 1];                                          \
    s16x8 hb0_[4], hb1_[4];                                                   \
    _Pragma("unroll")                                                         \
    for (int c = 0; c < 4; ++c) {                                             \
        hb0_[c] = *(const s16x8*)&(R0)[(c * 64 + l) * 8];                     \
        hb1_[c] = *(const s16x8*)&(R1)[(c * 64 + l) * 8];                     \
    }                                                                         \
    f32x4 a1_[8];                                                             \
    _Pragma("unroll")                                                         \
    for (int t2 = 0; t2 < 8; ++t2)                                            \
        a1_[t2] = *(const f32x4*)&b1lds[w][t2][q * 4];                        \
    /* phase3 even tiles (half 0) */                                          \
    _Pragma("unroll")                                                         \
    for (int c = 0; c < 4; ++c) {                                             \
        _Pragma("unroll")                                                     \
        for (int t2 = 0; t2 < 8; t2 += 2)                                     \
            a1_[t2] = MFMA16(wi1f[c][t2], hb0_[c], a1_[t2]);                  \
        _Pragma("unroll")                                                     \
        for (int t2 = 0; t2 < 8; t2 += 2)                                     \
            a1_[t2] = MFMA16(wh1f[c][t2], hb1_[c], a1_[t2]);                  \
    }                                                                         \
    /* phase3 odd tiles (half 1) */                                           \
    _Pragma("unroll")                                                         \
    for (int c = 0; c < 4; ++c) {                                             \
        _Pragma("unroll")                                                     \
        for (int t2 = 1; t2 < 8; t2 += 2)                                     \
            a1_[t2] = MFMA16(wi1f[c][t2], hb0_[c], a1_[t2]);                  \
        _Pragma("unroll")                                                     \
        for (int t2 = 1; t2 < 8; t2 += 2)                                     \
            a1_[t2] = MFMA16(wh1f[c][t2], hb1_[c], a1_[t2]);                  \
    }                                                                         \
    /* layer-1 pointwise half 0 (hides under phase1' MFMA issue) */           \
    PH4(0, W1B, fo0)                                                          \
    /* phase1': acc0 = Whh0 @ h0[T] */                                        \
    f32x4 a0_[8];                                                             \
    _Pragma("unroll")                                                         \
    for (int t2 = 0; t2 < 8; ++t2) { a0_[t2][0]=0.f; a0_[t2][1]=0.f; a0_[t2][2]=0.f; a0_[t2][3]=0.f; } \
    _Pragma("unroll")                                                         \
    for (int c = 0; c < 4; ++c) {                                             \
        _Pragma("unroll")                                                     \
        for (int t2 = 0; t2 < 8; ++t2)                                        \
            a0_[t2] = MFMA16(w0f[c][t2], hb0_[c], a0_[t2]);                   \
    }                                                                         \
    PH4(1, W1B, fo1)                                                          \
    PH2(0, W0B, fo0, xn_)                                                     \
    PH2(1, W0B, fo1, xn_)                                                     \
    __syncthreads();                                                          \
} while (0)

    #pragma unroll 1
    for (int t = 0; t < 510; t += 2) {
        ITER(t,     h0f0, h1f1, h0f1, h1f0);
        ITER(t + 1, h0f1, h1f0, h0f0, h1f1);
    }
    ITER(510, h0f0, h1f1, h0f1, h1f0);   // -> h0[511] in h0f1, h1[510] in h1f0

    // ---- epilogue t=511: gates1 only; final h1 -> headH (f32) ----
    {
        s16x8 hb0_[4], hb1_[4];
        #pragma unroll
        for (int c = 0; c < 4; ++c) {
            hb0_[c] = *(const s16x8*)&h0f1[(c * 64 + l) * 8];   // h0[511]
            hb1_[c] = *(const s16x8*)&h1f0[(c * 64 + l) * 8];   // h1[510]
        }
        f32x4 a1_[8];
        #pragma unroll
        for (int t2 = 0; t2 < 8; ++t2)
            a1_[t2] = *(const f32x4*)&b1lds[w][t2][q * 4];
        #pragma unroll
        for (int c = 0; c < 4; ++c) {
            #pragma unroll
            for (int t2 = 0; t2 < 8; ++t2) {
                a1_[t2] = MFMA16(wi1f[c][t2], hb0_[c], a1_[t2]);
                a1_[t2] = MFMA16(wh1f[c][t2], hb1_[c], a1_[t2]);
            }
        }
        #pragma unroll
        for (int h = 0; h < 2; ++h) {
            f32x4 hv;
            #pragma unroll
            for (int r = 0; r < 4; ++r) {
                const float ig = sigmoidf_(a1_[0 + h][r]);
                const float fg = sigmoidf_(a1_[2 + h][r]);
                const float gg = tanhf_(a1_[4 + h][r]);
                const float og = sigmoidf_(a1_[6 + h][r]);
                const float cc = fmaf(fg, c1_[h][r], ig * gg);
                hv[r] = og * tanhf_(cc);
            }
            *(f32x4*)&headH[n * HDIM + (h ? ub1 : ub0)] = hv;
        }
    }
    __syncthreads();

    // ---- head: hidden = relu(h @ W1^T + b1) ----
    #pragma unroll
    for (int rep = 0; rep < 4; ++rep) {
        const int idx = tid + rep * 256;     // 1024 = 16 batch * 64 hidden
        const int nn = idx >> 6, j = idx & 63;
        float s = b1[j];
        const float* wrow = W1 + j * HDIM;
        const float* hrow = headH + nn * HDIM;
        #pragma unroll
        for (int k = 0; k < HDIM; k += 4) {
            const f32x4 hv = *(const f32x4*)&hrow[k];
            const f32x4 wv = *(const f32x4*)&wrow[k];
            s += hv[0]*wv[0] + hv[1]*wv[1] + hv[2]*wv[2] + hv[3]*wv[3];
        }
        headL[nn * 64 + j] = fmaxf(s, 0.0f);
    }
    __syncthreads();

    if (tid < 128) {
        const int nn = tid >> 3, cls = tid & 7;
        float s = b2[cls];
        const float* wrow = W2 + cls * 64;
        const float* hrow = headL + nn * 64;
        #pragma unroll
        for (int k = 0; k < 64; k += 4) {
            const f32x4 hv = *(const f32x4*)&hrow[k];
            const f32x4 wv = *(const f32x4*)&wrow[k];
            s += hv[0]*wv[0] + hv[1]*wv[1] + hv[2]*wv[2] + hv[3]*wv[3];
        }
        out[(size_t)(b0 + nn) * 8 + cls] = s;
    }
}

extern "C" void kernel_launch(void* const* d_in, const int* in_sizes, int n_in,
                              void* d_out, int out_size, void* d_ws, size_t ws_size,
                              hipStream_t stream) {
    const float* x    = (const float*)d_in[0];
    const float* Wih0 = (const float*)d_in[1];
    const float* Whh0 = (const float*)d_in[2];
    const float* bih0 = (const float*)d_in[3];
    const float* bhh0 = (const float*)d_in[4];
    const float* Wih1 = (const float*)d_in[5];
    const float* Whh1 = (const float*)d_in[6];
    const float* bih1 = (const float*)d_in[7];
    const float* bhh1 = (const float*)d_in[8];
    const float* W1   = (const float*)d_in[9];
    const float* b1   = (const float*)d_in[10];
    const float* W2   = (const float*)d_in[11];
    const float* b2   = (const float*)d_in[12];
    float* outp = (float*)d_out;

    lstm_fused_kernel<<<128, 256, 0, stream>>>(
        x, Wih0, Whh0, bih0, bhh0, Wih1, Whh1, bih1, bhh1, W1, b1, W2, b2, outp);
}

// Round 6
// 954.352 us; speedup vs baseline: 1.6760x; 1.6760x over previous
//
#include <hip/hip_runtime.h>
#include <stdint.h>

typedef float f32x4 __attribute__((ext_vector_type(4)));
typedef short s16x8 __attribute__((ext_vector_type(8)));
typedef short s16x4 __attribute__((ext_vector_type(4)));
typedef uint32_t u32x4 __attribute__((ext_vector_type(4)));

#define HDIM 128
#define TLEN 512
#define BT 16

__device__ __forceinline__ unsigned short f2bf(float f) {
    union { float f; uint32_t u; } v; v.f = f;
    uint32_t r = v.u + 0x7FFFu + ((v.u >> 16) & 1u);
    return (unsigned short)(r >> 16);
}
__device__ __forceinline__ float bfhi(uint32_t u){ union{uint32_t u;float f;}v; v.u = u & 0xFFFF0000u; return v.f; }
__device__ __forceinline__ float bflo(uint32_t u){ union{uint32_t u;float f;}v; v.u = u << 16; return v.f; }
__device__ __forceinline__ float bf2f(short s){ union{uint32_t u;float f;}v; v.u = ((uint32_t)(unsigned short)s) << 16; return v.f; }

__device__ __forceinline__ float sigmoidf_(float x){
    float e = __expf(-x);
    return __builtin_amdgcn_rcpf(1.0f + e);
}
__device__ __forceinline__ float tanhf_(float x){
    float e = __expf(2.0f * x);
    return 1.0f - 2.0f * __builtin_amdgcn_rcpf(1.0f + e);
}

#define MFMA16(A, B, C) __builtin_amdgcn_mfma_f32_16x16x32_bf16((A), (B), (C), 0, 0, 0)

__global__ __launch_bounds__(512, 2) void lstm_fused_kernel(
    const float* __restrict__ x,      // (2048,512,1)
    const float* __restrict__ Wih0,   // (512,1)
    const float* __restrict__ Whh0,   // (512,128)
    const float* __restrict__ bih0,
    const float* __restrict__ bhh0,
    const float* __restrict__ Wih1,   // (512,128)
    const float* __restrict__ Whh1,   // (512,128)
    const float* __restrict__ bih1,
    const float* __restrict__ bhh1,
    const float* __restrict__ W1,     // (64,128)
    const float* __restrict__ b1,     // (64)
    const float* __restrict__ W2,     // (8,64)
    const float* __restrict__ b2,     // (8)
    float* __restrict__ out)          // (2048,8)
{
    // Whh1 fragment-ordered in LDS (128 KB, streamed by L1 team only);
    // ping-pong h fragments; tiny b1 broadcast table. Head scratch aliases wh1lds.
    __shared__ __align__(16) short wh1lds[65536];                 // 128 KB
    __shared__ __align__(16) short h0f0[2048], h0f1[2048];
    __shared__ __align__(16) short h1f0[2048], h1f1[2048];
    __shared__ __align__(16) float b1lds[4][8][16];               // 2 KB

    const int tid = threadIdx.x;
    const int w   = tid >> 6;
    const int wl  = w & 3;          // wave index within team
    const bool isL0 = (w < 4);      // waves 0-3: layer 0 ; waves 4-7: layer 1
    const int l = tid & 63;
    const int n = l & 15;           // batch col
    const int q = l >> 4;           // k-group / row-quad
    const int b0 = blockIdx.x * BT;
    const float* xrow = x + (size_t)(b0 + n) * TLEN;

    // ---- stage Whh1 into LDS, fragment-ordered per L1 wave (all 512 threads) ----
    for (int s2 = tid; s2 < 8192; s2 += 512) {
        const int ll = s2 & 63, t2 = (s2 >> 6) & 7, cc = (s2 >> 9) & 3, wv = s2 >> 11;
        const int row = (t2 >> 1) * 128 + 32 * wv + 16 * (t2 & 1) + (ll & 15);
        const int k0  = cc * 32 + (ll >> 4) * 8;
        const float* p = Whh1 + row * HDIM + k0;
        s16x8 a;
        #pragma unroll
        for (int j = 0; j < 8; ++j) a[j] = (short)f2bf(p[j]);
        *(s16x8*)&wh1lds[s2 * 8] = a;
    }
    // ---- b1 broadcast table (512 entries, one per thread) ----
    {
        const int idx = tid;
        const int wv = idx >> 7, t2 = (idx >> 4) & 7, j = idx & 15;
        const int row = (t2 >> 1) * 128 + 32 * wv + 16 * (t2 & 1) + j;
        b1lds[wv][t2][j] = bih1[row] + bhh1[row];
    }
    // zero h1[-1]
    for (int s2 = tid; s2 < 1024; s2 += 512) ((uint32_t*)h1f1)[s2] = 0u;

    // B-fragment write slots for this lane's unit quads (h=0 / h=1)
    const int ub0 = 32 * wl + 4 * q;
    const int ub1 = ub0 + 16;
    const int fo0 = ((ub0 >> 5) * 64 + n + 16 * ((ub0 >> 3) & 3)) * 8 + (ub0 & 7);
    const int fo1 = ((ub1 >> 5) * 64 + n + 16 * ((ub1 >> 3) & 3)) * 8 + (ub1 & 7);

#define L0ITER(K, R0, W0) do {                                                \
    const int xi_ = (K) + 1;                                                  \
    const float xv_ = xrow[xi_ < TLEN ? xi_ : (TLEN - 1)];                    \
    s16x8 hb_[4];                                                             \
    _Pragma("unroll")                                                         \
    for (int c = 0; c < 4; ++c) hb_[c] = *(const s16x8*)&(R0)[(c * 64 + l) * 8]; \
    f32x4 a_[8];                                                              \
    _Pragma("unroll")                                                         \
    for (int t2 = 0; t2 < 8; ++t2) {                                          \
        _Pragma("unroll")                                                     \
        for (int r = 0; r < 4; ++r)                                           \
            a_[t2][r] = fmaf(bfhi(bwx[t2][r]), xv_, bflo(bwx[t2][r]));        \
    }                                                                         \
    _Pragma("unroll")                                                         \
    for (int c = 0; c < 4; ++c) {                                             \
        _Pragma("unroll")                                                     \
        for (int t2 = 0; t2 < 8; ++t2)                                        \
            a_[t2] = MFMA16(w0f[c][t2], hb_[c], a_[t2]);                      \
    }                                                                         \
    _Pragma("unroll")                                                         \
    for (int h = 0; h < 2; ++h) {                                             \
        s16x4 hw;                                                             \
        _Pragma("unroll")                                                     \
        for (int r = 0; r < 4; ++r) {                                         \
            const float ig = sigmoidf_(a_[0 + h][r]);                         \
            const float fg = sigmoidf_(a_[2 + h][r]);                         \
            const float gg = tanhf_(a_[4 + h][r]);                            \
            const float og = sigmoidf_(a_[6 + h][r]);                         \
            const float cc = fmaf(fg, c0_[h][r], ig * gg);                    \
            c0_[h][r] = cc;                                                   \
            hw[r] = (short)f2bf(og * tanhf_(cc));                             \
        }                                                                     \
        *(s16x4*)&(W0)[h ? fo1 : fo0] = hw;                                   \
    }                                                                         \
    __syncthreads();                                                          \
} while (0)

#define L1ITER(K, R0, R1, W1) do {                                            \
    s16x8 hb0_[4], hb1_[4];                                                   \
    _Pragma("unroll")                                                         \
    for (int c = 0; c < 4; ++c) {                                             \
        hb0_[c] = *(const s16x8*)&(R0)[(c * 64 + l) * 8];                     \
        hb1_[c] = *(const s16x8*)&(R1)[(c * 64 + l) * 8];                     \
    }                                                                         \
    f32x4 a_[8];                                                              \
    _Pragma("unroll")                                                         \
    for (int t2 = 0; t2 < 8; ++t2)                                            \
        a_[t2] = *(const f32x4*)&b1lds[wl][t2][q * 4];                        \
    _Pragma("unroll")                                                         \
    for (int c = 0; c < 4; ++c) {                                             \
        _Pragma("unroll")                                                     \
        for (int t2 = 0; t2 < 8; ++t2)                                        \
            a_[t2] = MFMA16(wi1f[c][t2], hb0_[c], a_[t2]);                    \
    }                                                                         \
    _Pragma("unroll")                                                         \
    for (int c = 0; c < 4; ++c) {                                             \
        s16x8 wt_[8];                                                         \
        _Pragma("unroll")                                                     \
        for (int t2 = 0; t2 < 8; ++t2)                                        \
            wt_[t2] = *(const s16x8*)&wh1lds[(((wl * 4 + c) * 8 + t2) * 64 + l) * 8]; \
        _Pragma("unroll")                                                     \
        for (int t2 = 0; t2 < 8; ++t2)                                        \
            a_[t2] = MFMA16(wt_[t2], hb1_[c], a_[t2]);                        \
    }                                                                         \
    _Pragma("unroll")                                                         \
    for (int h = 0; h < 2; ++h) {                                             \
        s16x4 hw;                                                             \
        _Pragma("unroll")                                                     \
        for (int r = 0; r < 4; ++r) {                                         \
            const float ig = sigmoidf_(a_[0 + h][r]);                         \
            const float fg = sigmoidf_(a_[2 + h][r]);                         \
            const float gg = tanhf_(a_[4 + h][r]);                            \
            const float og = sigmoidf_(a_[6 + h][r]);                         \
            const float cc = fmaf(fg, c1_[h][r], ig * gg);                    \
            c1_[h][r] = cc;                                                   \
            hw[r] = (short)f2bf(og * tanhf_(cc));                             \
        }                                                                     \
        *(s16x4*)&(W1)[h ? fo1 : fo0] = hw;                                   \
    }                                                                         \
    __syncthreads();                                                          \
} while (0)

    if (isL0) {
        // ---- L0 team: Whh0 fully in registers ----
        s16x8 w0f[4][8];
        #pragma unroll
        for (int c = 0; c < 4; ++c) {
            #pragma unroll
            for (int t2 = 0; t2 < 8; ++t2) {
                const int row = (t2 >> 1) * 128 + 32 * wl + 16 * (t2 & 1) + n;
                const int k0 = c * 32 + q * 8;
                const float* p = Whh0 + row * HDIM + k0;
                s16x8 a;
                #pragma unroll
                for (int j = 0; j < 8; ++j) a[j] = (short)f2bf(p[j]);
                w0f[c][t2] = a;
            }
        }
        // packed (bias0, wx) per owned gate-row
        u32x4 bwx[8];
        #pragma unroll
        for (int t2 = 0; t2 < 8; ++t2) {
            #pragma unroll
            for (int r = 0; r < 4; ++r) {
                const int row = (t2 >> 1) * 128 + 32 * wl + 16 * (t2 & 1) + 4 * q + r;
                bwx[t2][r] = ((uint32_t)f2bf(Wih0[row]) << 16) | f2bf(bih0[row] + bhh0[row]);
            }
        }
        float c0_[2][4] = {{0.f,0.f,0.f,0.f},{0.f,0.f,0.f,0.f}};

        // prologue: h0[0] = pointwise(b0 + wx*x[0]) ; h0[-1]=0 so no MFMA
        {
            const float x0 = xrow[0];
            #pragma unroll
            for (int h = 0; h < 2; ++h) {
                s16x4 hw;
                #pragma unroll
                for (int r = 0; r < 4; ++r) {
                    const float pi = fmaf(bfhi(bwx[0 + h][r]), x0, bflo(bwx[0 + h][r]));
                    const float pg = fmaf(bfhi(bwx[4 + h][r]), x0, bflo(bwx[4 + h][r]));
                    const float po = fmaf(bfhi(bwx[6 + h][r]), x0, bflo(bwx[6 + h][r]));
                    const float ig = sigmoidf_(pi);
                    const float gg = tanhf_(pg);
                    const float og = sigmoidf_(po);
                    const float cc = ig * gg;          // f * c(-1) = 0
                    c0_[h][r] = cc;
                    hw[r] = (short)f2bf(og * tanhf_(cc));
                }
                *(s16x4*)&h0f0[h ? fo1 : fo0] = hw;
            }
        }
        __syncthreads();   // staging + prologue visible (pairs with L1's pre-loop barrier)

        #pragma unroll 1
        for (int k = 0; k < TLEN; k += 2) {
            L0ITER(k,     h0f0, h0f1);
            L0ITER(k + 1, h0f1, h0f0);
        }
    } else {
        // ---- L1 team: Wih1 in registers, Whh1 streamed from LDS ----
        s16x8 wi1f[4][8];
        #pragma unroll
        for (int c = 0; c < 4; ++c) {
            #pragma unroll
            for (int t2 = 0; t2 < 8; ++t2) {
                const int row = (t2 >> 1) * 128 + 32 * wl + 16 * (t2 & 1) + n;
                const int k0 = c * 32 + q * 8;
                const float* p = Wih1 + row * HDIM + k0;
                s16x8 a;
                #pragma unroll
                for (int j = 0; j < 8; ++j) a[j] = (short)f2bf(p[j]);
                wi1f[c][t2] = a;
            }
        }
        float c1_[2][4] = {{0.f,0.f,0.f,0.f},{0.f,0.f,0.f,0.f}};

        __syncthreads();   // pairs with L0's pre-loop barrier

        #pragma unroll 1
        for (int k = 0; k < TLEN; k += 2) {
            L1ITER(k,     h0f0, h1f1, h1f0);
            L1ITER(k + 1, h0f1, h1f0, h1f1);
        }
    }

    // ---- head: final h1 (t=511) is in h1f1; L1 lanes re-read their own slots ----
    float* headH = (float*)wh1lds;            // [16][128] f32 (aliases wh1lds)
    float* headL = headH + 16 * HDIM;         // [16][64]
    if (!isL0) {
        #pragma unroll
        for (int h = 0; h < 2; ++h) {
            const s16x4 hv = *(const s16x4*)&h1f1[h ? fo1 : fo0];
            f32x4 hf;
            #pragma unroll
            for (int r = 0; r < 4; ++r) hf[r] = bf2f(hv[r]);
            *(f32x4*)&headH[n * HDIM + (h ? ub1 : ub0)] = hf;
        }
    }
    __syncthreads();

    #pragma unroll
    for (int rep = 0; rep < 2; ++rep) {
        const int idx = tid + rep * 512;     // 1024 = 16 batch * 64 hidden
        const int nn = idx >> 6, j = idx & 63;
        float s = b1[j];
        const float* wrow = W1 + j * HDIM;
        const float* hrow = headH + nn * HDIM;
        #pragma unroll
        for (int k = 0; k < HDIM; k += 4) {
            const f32x4 hv = *(const f32x4*)&hrow[k];
            const f32x4 wv = *(const f32x4*)&wrow[k];
            s += hv[0]*wv[0] + hv[1]*wv[1] + hv[2]*wv[2] + hv[3]*wv[3];
        }
        headL[nn * 64 + j] = fmaxf(s, 0.0f);
    }
    __syncthreads();

    if (tid < 128) {
        const int nn = tid >> 3, cls = tid & 7;
        float s = b2[cls];
        const float* wrow = W2 + cls * 64;
        const float* hrow = headL + nn * 64;
        #pragma unroll
        for (int k = 0; k < 64; k += 4) {
            const f32x4 hv = *(const f32x4*)&hrow[k];
            const f32x4 wv = *(const f32x4*)&wrow[k];
            s += hv[0]*wv[0] + hv[1]*wv[1] + hv[2]*wv[2] + hv[3]*wv[3];
        }
        out[(size_t)(b0 + nn) * 8 + cls] = s;
    }
}

extern "C" void kernel_launch(void* const* d_in, const int* in_sizes, int n_in,
                              void* d_out, int out_size, void* d_ws, size_t ws_size,
                              hipStream_t stream) {
    const float* x    = (const float*)d_in[0];
    const float* Wih0 = (const float*)d_in[1];
    const float* Whh0 = (const float*)d_in[2];
    const float* bih0 = (const float*)d_in[3];
    const float* bhh0 = (const float*)d_in[4];
    const float* Wih1 = (const float*)d_in[5];
    const float* Whh1 = (const float*)d_in[6];
    const float* bih1 = (const float*)d_in[7];
    const float* bhh1 = (const float*)d_in[8];
    const float* W1   = (const float*)d_in[9];
    const float* b1   = (const float*)d_in[10];
    const float* W2   = (const float*)d_in[11];
    const float* b2   = (const float*)d_in[12];
    float* outp = (float*)d_out;

    lstm_fused_kernel<<<128, 512, 0, stream>>>(
        x, Wih0, Whh0, bih0, bhh0, Wih1, Whh1, bih1, bhh1, W1, b1, W2, b2, outp);
}